// Round 1
// baseline (105.163 us; speedup 1.0000x reference)
//
#include <hip/hip_runtime.h>
#include <math.h>

#define IN_DIM 768
#define OUT_DIM 768
#define BATCH 32
#define NUM_F 8
#define SPAD 12            // padded float stride per (b,i) row of S (48B, float4-aligned)

#define O_TILE 16          // outputs per block
#define I_SPLIT 16         // blocks along i
#define I_CHUNK (IN_DIM / I_SPLIT)   // 48

// Kernel 1: build S[b][i][0..7] = sin(grid[j]*x), S[b][i][8] = silu(x); seed y = bias.
__global__ __launch_bounds__(256) void build_S(const float* __restrict__ x,
                                               const float* __restrict__ grid,
                                               const float* __restrict__ bias_w,
                                               float* __restrict__ S,
                                               float* __restrict__ y) {
    int idx = blockIdx.x * 256 + threadIdx.x;          // 0 .. 24575 == b*768 + i
    if (idx >= BATCH * IN_DIM) return;
    float xv = x[idx];
    float* out = S + (size_t)idx * SPAD;
    float4 a, b4;
    a.x  = __sinf(grid[0] * xv);
    a.y  = __sinf(grid[1] * xv);
    a.z  = __sinf(grid[2] * xv);
    a.w  = __sinf(grid[3] * xv);
    b4.x = __sinf(grid[4] * xv);
    b4.y = __sinf(grid[5] * xv);
    b4.z = __sinf(grid[6] * xv);
    b4.w = __sinf(grid[7] * xv);
    *(float4*)(out)     = a;
    *(float4*)(out + 4) = b4;
    out[8] = xv / (1.0f + __expf(-xv));                // silu
    // y[b][o] = bias_w[o]
    y[idx] = bias_w[idx % OUT_DIM];
}

// Kernel 2: y[b,o] += sum over an i-chunk of (ssp*dot(coef,S_sin) + sb*silu)
__global__ __launch_bounds__(256) void fused_reduce(const float* __restrict__ S,
                                                    const float* __restrict__ coef,
                                                    const float* __restrict__ scale_base,
                                                    const float* __restrict__ scale_sp,
                                                    float* __restrict__ y) {
    __shared__ float red[8 * 512];                     // [g][b*O_TILE+ol], 16 KB
    const int t  = threadIdx.x;
    const int b  = t & 31;                             // batch lane
    const int g  = t >> 5;                             // i-group 0..7
    const int ob = blockIdx.x / I_SPLIT;
    const int is = blockIdx.x % I_SPLIT;
    const int o0 = ob * O_TILE;
    const int i0 = is * I_CHUNK;

    float acc[O_TILE];
#pragma unroll
    for (int ol = 0; ol < O_TILE; ++ol) acc[ol] = 0.0f;

    for (int i = i0 + g; i < i0 + I_CHUNK; i += 8) {   // 6 iterations
        const float4* sp = (const float4*)(S + (size_t)(b * IN_DIM + i) * SPAD);
        const float4 sA = sp[0];
        const float4 sB = sp[1];
        const float  s8 = S[(size_t)(b * IN_DIM + i) * SPAD + 8];
#pragma unroll
        for (int ol = 0; ol < O_TILE; ++ol) {
            const int n = (o0 + ol) * IN_DIM + i;      // wave-uniform per b-group
            const float4* cp = (const float4*)(coef + (size_t)n * 8);
            const float4 c0 = cp[0];
            const float4 c1 = cp[1];
            const float ssp = scale_sp[n];
            const float sb  = scale_base[n];
            float dot = c0.x * sA.x + c0.y * sA.y + c0.z * sA.z + c0.w * sA.w
                      + c1.x * sB.x + c1.y * sB.y + c1.z * sB.z + c1.w * sB.w;
            acc[ol] += ssp * dot + sb * s8;
        }
    }

#pragma unroll
    for (int ol = 0; ol < O_TILE; ++ol)
        red[g * 512 + b * O_TILE + ol] = acc[ol];
    __syncthreads();

#pragma unroll
    for (int rep = 0; rep < 2; ++rep) {
        const int idx2 = t + rep * 256;                // 0..511 covers 32b x 16ol
        const int b2  = idx2 >> 4;
        const int ol2 = idx2 & 15;
        float sum = 0.0f;
#pragma unroll
        for (int g2 = 0; g2 < 8; ++g2) sum += red[g2 * 512 + idx2];
        atomicAdd(&y[b2 * OUT_DIM + o0 + ol2], sum);
    }
}

extern "C" void kernel_launch(void* const* d_in, const int* in_sizes, int n_in,
                              void* d_out, int out_size, void* d_ws, size_t ws_size,
                              hipStream_t stream) {
    const float* x          = (const float*)d_in[0];  // 32*12*64 = 24576
    const float* grid       = (const float*)d_in[1];  // 8
    const float* coef       = (const float*)d_in[2];  // 589824*8
    const float* bias_w     = (const float*)d_in[3];  // 768
    const float* scale_base = (const float*)d_in[4];  // 589824
    const float* scale_sp   = (const float*)d_in[5];  // 589824
    float* y = (float*)d_out;                          // 32*768
    float* S = (float*)d_ws;                           // needs 24576*12*4 = 1.18 MB

    build_S<<<(BATCH * IN_DIM + 255) / 256, 256, 0, stream>>>(x, grid, bias_w, S, y);
    fused_reduce<<<(OUT_DIM / O_TILE) * I_SPLIT, 256, 0, stream>>>(S, coef, scale_base,
                                                                   scale_sp, y);
}